// Round 7
// baseline (312.876 us; speedup 1.0000x reference)
//
#include <hip/hip_runtime.h>

// ---------------------------------------------------------------------------
// HetGAT critic on MI355X (gfx950), bf16-MFMA implementation.
//
// Algebraic simplification: softmax(axis=1) + einsum('bij,bjf->bf') makes the
// attention sum to exactly 1 per column => h_prime = (sum_nodes emb) @ gat_w.
// gat_a / adj / leaky_relu / softmax are dead code.
//
// Round-6 fix: k_scan's VGPR_Count=96 showed the 24 "loop-invariant" weight
// fragments (96 VGPR worth) were NOT register-resident -- the compiler
// rematerialized them as per-step global reloads (384 addr segments/wave/step,
// the real bottleneck).  Weights are now loaded as int32x4 and passed through
// an opaque asm copy (cannot be rematerialized) => forced resident.
// Same treatment for k_ue_l1l2's 9 frags.  k_prep transpose now reads
// coalesced / writes scattered.
//
// MFMA v_mfma_f32_16x16x32_bf16 layouts:
//   A[m][k]: m=lane&15, k=(lane>>4)*8+i   (8 contiguous bf16 per lane)
//   B[k][n]: n=lane&15, k=(lane>>4)*8+i   (weights stored transposed [N][K])
//   D[m][n]: n=lane&15, m=(lane>>4)*4+reg
// ---------------------------------------------------------------------------

typedef unsigned short u16;
typedef __bf16  bf16x8  __attribute__((ext_vector_type(8)));
typedef short   short8  __attribute__((ext_vector_type(8)));
typedef u16     u16x4   __attribute__((ext_vector_type(4)));
typedef float   floatx4 __attribute__((ext_vector_type(4)));
typedef int     int32x4 __attribute__((ext_vector_type(4)));

#define DEVI __device__ __forceinline__
#define MFMA(a, b, c) __builtin_amdgcn_mfma_f32_16x16x32_bf16((a), (b), (c), 0, 0, 0)
#define B8(x) __builtin_bit_cast(bf16x8, (x))
#define KEEP(x) asm volatile("" : "+v"(x))

DEVI u16 f2b(float f) {                       // f32 -> bf16 bits, RNE
    unsigned u = __float_as_uint(f);
    u += 0x7fffu + ((u >> 16) & 1u);
    return (u16)(u >> 16);
}
DEVI float b2f(u16 s) { return __uint_as_float(((unsigned)s) << 16); }
DEVI float sigm(float x) { return 1.f / (1.f + __expf(-x)); }
DEVI float tanh_(float x) { return 1.f - 2.f / (__expf(2.f * x) + 1.f); }

DEVI bf16x8 ldfrag(const u16* q) {            // 8 contiguous bf16 (16B aligned)
    return *reinterpret_cast<const bf16x8*>(q);
}
DEVI int32x4 ldfrag_i(const u16* q) {
    return *reinterpret_cast<const int32x4*>(q);
}
DEVI bf16x8 ldfrag_f32(const float* q) {      // 8 contiguous f32 -> bf16 frag
    float4 u = *reinterpret_cast<const float4*>(q);
    float4 v = *reinterpret_cast<const float4*>(q + 4);
    short8 pk;
    pk[0] = (short)f2b(u.x); pk[1] = (short)f2b(u.y);
    pk[2] = (short)f2b(u.z); pk[3] = (short)f2b(u.w);
    pk[4] = (short)f2b(v.x); pk[5] = (short)f2b(v.y);
    pk[6] = (short)f2b(v.z); pk[7] = (short)f2b(v.w);
    return __builtin_bit_cast(bf16x8, pk);
}

// bf16 weight offsets inside ws (elements)
enum : int {
    O_UE_W1T  = 0,        // [128][160]
    O_UE_W2T  = 20480,    // [128][128]
    O_UE_WIH0 = 36864,    // [384][128]
    O_UE_WHH0 = 86016,
    O_UE_WIH1 = 135168,
    O_UE_WHH1 = 184320,
    O_BS_W1T  = 233472,   // [128][320]
    O_BS_W2T  = 274432,
    O_BS_WIH0 = 290816,
    O_BS_WIH1 = 339968,
    O_GATWT   = 389120,   // [128][128]
    O_EV1T    = 405504,   // [128][128]
};
// ws byte offsets
#define WB_X2   1048576u
#define WB_Y0   34603008u
#define WB_SSUM 139460608u

// ---------------------------------------------------------------------------
__global__ __launch_bounds__(256) void k_prep(
    const float* __restrict__ ue1, const float* __restrict__ ue2,
    const float* __restrict__ uw0, const float* __restrict__ uh0,
    const float* __restrict__ uw1, const float* __restrict__ uh1,
    const float* __restrict__ bs1, const float* __restrict__ bs2,
    const float* __restrict__ bw0, const float* __restrict__ bw1,
    const float* __restrict__ gw,  const float* __restrict__ e1,
    u16* __restrict__ out)
{
    const int tid = blockIdx.x * blockDim.x + threadIdx.x;
    const int stride = gridDim.x * blockDim.x;
    auto cvt = [&](const float* s, int off, int n) {
        for (int i = tid; i < n; i += stride) out[off + i] = f2b(s[i]);
    };
    // [K,N] -> [N,K]; iterate input-linear (coalesced reads, scattered writes)
    auto tcv = [&](const float* s, int off, int K, int N) {
        const int tot = K * N;
        for (int j = tid; j < tot; j += stride) {
            int kk = j / N, nn = j - kk * N;
            out[off + nn * K + kk] = f2b(s[j]);
        }
    };
    tcv(ue1, O_UE_W1T, 160, 128);  tcv(ue2, O_UE_W2T, 128, 128);
    cvt(uw0, O_UE_WIH0, 49152);    cvt(uh0, O_UE_WHH0, 49152);
    cvt(uw1, O_UE_WIH1, 49152);    cvt(uh1, O_UE_WHH1, 49152);
    tcv(bs1, O_BS_W1T, 320, 128);  tcv(bs2, O_BS_W2T, 128, 128);
    cvt(bw0, O_BS_WIH0, 49152);    cvt(bw1, O_BS_WIH1, 49152);
    tcv(gw,  O_GATWT, 128, 128);   tcv(e1,  O_EV1T, 128, 128);
}

// ---------------------------------------------------------------------------
// UE l1(relu) + l2(sigmoid), fused.  512 thr, 128 rows/block, grid 1024.
// Weight frags opaque-copied => guaranteed register-resident.
__global__ __launch_bounds__(512, 2) void k_ue_l1l2(
    const float* __restrict__ s, const float* __restrict__ a,
    const u16* __restrict__ W1T, const float* __restrict__ b1,
    const u16* __restrict__ W2T, const float* __restrict__ b2,
    u16* __restrict__ X2)
{
    __shared__ __align__(16) u16 A1[128][168];   // 160 cols + pad
    __shared__ __align__(16) u16 H[128][136];    // 128 cols + pad
    const int tid = threadIdx.x;
    const int w = tid >> 6, lane = tid & 63;
    const int lm = lane & 15, lg = lane >> 4;
    const int r0 = blockIdx.x * 128;

    int32x4 bw1[5], bw2[4];
#pragma unroll
    for (int ks = 0; ks < 5; ++ks)
        bw1[ks] = ldfrag_i(W1T + (w * 16 + lm) * 160 + ks * 32 + lg * 8);
#pragma unroll
    for (int ks = 0; ks < 4; ++ks)
        bw2[ks] = ldfrag_i(W2T + (w * 16 + lm) * 128 + ks * 32 + lg * 8);
#pragma unroll
    for (int ks = 0; ks < 5; ++ks) KEEP(bw1[ks]);
#pragma unroll
    for (int ks = 0; ks < 4; ++ks) KEEP(bw2[ks]);
    const float bias1 = b1[w * 16 + lm];
    const float bias2 = b2[w * 16 + lm];

#pragma unroll
    for (int it = 0; it < 8; ++it) {
        const int fidx = it * 512 + tid;
        const int row = fidx >> 5, c4 = fidx & 31;
        const int r = r0 + row, bb = r >> 5, tt = r & 31;
        float4 v = *reinterpret_cast<const float4*>(s + (size_t)bb * 4352 + tt * 128 + c4 * 4);
        u16x4 p = {f2b(v.x), f2b(v.y), f2b(v.z), f2b(v.w)};
        *reinterpret_cast<u16x4*>(&A1[row][c4 * 4]) = p;
    }
#pragma unroll
    for (int it = 0; it < 2; ++it) {
        const int fidx = it * 512 + tid;
        const int row = fidx >> 3, c4 = fidx & 7;
        const int r = r0 + row, bb = r >> 5, tt = r & 31;
        float4 v = *reinterpret_cast<const float4*>(a + (size_t)bb * 1088 + tt * 32 + c4 * 4);
        u16x4 p = {f2b(v.x), f2b(v.y), f2b(v.z), f2b(v.w)};
        *reinterpret_cast<u16x4*>(&A1[row][128 + c4 * 4]) = p;
    }
    __syncthreads();

#pragma unroll
    for (int mt = 0; mt < 8; ++mt) {
        bf16x8 af[5];
#pragma unroll
        for (int ks = 0; ks < 5; ++ks)
            af[ks] = ldfrag(&A1[mt * 16 + lm][ks * 32 + lg * 8]);
        floatx4 acc = {0.f, 0.f, 0.f, 0.f};
#pragma unroll
        for (int ks = 0; ks < 5; ++ks) acc = MFMA(af[ks], B8(bw1[ks]), acc);
#pragma unroll
        for (int i = 0; i < 4; ++i) {
            float x = acc[i] + bias1;
            H[mt * 16 + lg * 4 + i][w * 16 + lm] = f2b(x > 0.f ? x : 0.f);
        }
    }
    __syncthreads();

#pragma unroll
    for (int mt = 0; mt < 8; ++mt) {
        bf16x8 af[4];
#pragma unroll
        for (int ks = 0; ks < 4; ++ks)
            af[ks] = ldfrag(&H[mt * 16 + lm][ks * 32 + lg * 8]);
        floatx4 acc = {0.f, 0.f, 0.f, 0.f};
#pragma unroll
        for (int ks = 0; ks < 4; ++ks) acc = MFMA(af[ks], B8(bw2[ks]), acc);
#pragma unroll
        for (int i = 0; i < 4; ++i)
            X2[(size_t)(r0 + mt * 16 + lg * 4 + i) * 128 + w * 16 + lm] =
                f2b(sigm(acc[i] + bias2));
    }
}

// ---------------------------------------------------------------------------
// Fused GRU layer: gi GEMM + time scan.  Block = 16 batch rows, 8 waves;
// wave w owns dh cols [w*16,w*16+16).  Wih/Whh frags opaque-copied =>
// register-resident (the round-6 VGPR=96 reload bug).  Depth-2 x prefetch,
// merged r/z accumulators, setprio around MFMA, one lgkm barrier per step.
#define SCAN_STEP(RBUF, WBUF, XA, TCUR, PREF_T)                               \
  {                                                                           \
    bf16x8 af[4];                                                             \
    _Pragma("unroll") for (int ks = 0; ks < 4; ++ks)                          \
        af[ks] = ldfrag(&RBUF[lm][ks * 32 + lg * 8]);                         \
    floatx4 accR{0.f,0.f,0.f,0.f}, accZ{0.f,0.f,0.f,0.f};                     \
    floatx4 accGN{0.f,0.f,0.f,0.f}, accHN{0.f,0.f,0.f,0.f};                   \
    __builtin_amdgcn_s_setprio(1);                                            \
    _Pragma("unroll") for (int ks = 0; ks < 4; ++ks) {                        \
        accR  = MFMA(XA[ks], B8(bwi[0][ks]), accR);                           \
        accZ  = MFMA(XA[ks], B8(bwi[1][ks]), accZ);                           \
        accGN = MFMA(XA[ks], B8(bwi[2][ks]), accGN);                          \
    }                                                                         \
    if ((PREF_T) < 32) {                                                      \
        _Pragma("unroll") for (int ks = 0; ks < 4; ++ks)                      \
            XA[ks] = ldfrag(xp + (PREF_T) * 128 + ks * 32);                   \
    }                                                                         \
    _Pragma("unroll") for (int ks = 0; ks < 4; ++ks) {                        \
        accR = MFMA(af[ks], B8(bwh[0][ks]), accR);                            \
        accZ = MFMA(af[ks], B8(bwh[1][ks]), accZ);                            \
        accHN = MFMA(af[ks], B8(bwh[2][ks]), accHN);                          \
    }                                                                         \
    __builtin_amdgcn_s_setprio(0);                                            \
    _Pragma("unroll") for (int i = 0; i < 4; ++i) {                           \
        const float rr = sigm(accR[i] + br);                                  \
        const float zz = sigm(accZ[i] + bz);                                  \
        const float nn = tanh_(accGN[i] + bni + rr * (accHN[i] + bnh));       \
        const float hn = (1.f - zz) * nn + zz * hreg[i];                      \
        hreg[i] = hn;                                                         \
        if (MODE == 1) ssum[i] += hn;                                         \
        const u16 hv = f2b(hn);                                               \
        WBUF[lg * 4 + i][c] = hv;                                             \
        if (MODE == 0)                                                        \
            Y[((size_t)(b0 + lg * 4 + i) * 32 + (TCUR)) * 128 + c] = hv;      \
    }                                                                         \
    __builtin_amdgcn_sched_barrier(0);                                        \
    asm volatile("s_waitcnt lgkmcnt(0)" ::: "memory");                        \
    __builtin_amdgcn_s_barrier();                                             \
    __builtin_amdgcn_sched_barrier(0);                                        \
  }

template <int MODE>
__global__ __launch_bounds__(512, 2) void k_scan(
    const u16* __restrict__ X, const u16* __restrict__ WIH,
    const u16* __restrict__ WHH,
    const float* __restrict__ bih, const float* __restrict__ bhh,
    u16* __restrict__ Y, float* __restrict__ Ssum)
{
    __shared__ __align__(16) u16 hb0[16][136];
    __shared__ __align__(16) u16 hb1[16][136];
    const int w = threadIdx.x >> 6, lane = threadIdx.x & 63;
    const int lm = lane & 15, lg = lane >> 4;
    const int b0 = blockIdx.x * 16;
    const int c = w * 16 + lm;

    int32x4 bwh[3][4], bwi[3][4];
#pragma unroll
    for (int g = 0; g < 3; ++g)
#pragma unroll
        for (int ks = 0; ks < 4; ++ks) {
            bwh[g][ks] = ldfrag_i(WHH + (g * 128 + c) * 128 + ks * 32 + lg * 8);
            bwi[g][ks] = ldfrag_i(WIH + (g * 128 + c) * 128 + ks * 32 + lg * 8);
        }
    // opaque copies: results of asm cannot be rematerialized => resident
#pragma unroll
    for (int g = 0; g < 3; ++g)
#pragma unroll
        for (int ks = 0; ks < 4; ++ks) {
            KEEP(bwh[g][ks]);
            KEEP(bwi[g][ks]);
        }

    for (int i = threadIdx.x; i < 16 * 136; i += 512) {
        ((u16*)hb0)[i] = 0; ((u16*)hb1)[i] = 0;
    }

    const float br  = bih[c] + bhh[c];
    const float bz  = bih[128 + c] + bhh[128 + c];
    const float bni = bih[256 + c], bnh = bhh[256 + c];

    const u16* xp = X + (size_t)(b0 + lm) * 32 * 128 + lg * 8;
    bf16x8 xa[4], xb[4];
#pragma unroll
    for (int ks = 0; ks < 4; ++ks) {
        xa[ks] = ldfrag(xp + ks * 32);            // t=0
        xb[ks] = ldfrag(xp + 128 + ks * 32);      // t=1
    }

    float hreg[4] = {}, ssum[4] = {};
    __syncthreads();

    for (int tt = 0; tt < 32; tt += 2) {
        SCAN_STEP(hb0, hb1, xa, tt,     tt + 2);
        SCAN_STEP(hb1, hb0, xb, tt + 1, tt + 3);
    }
    if (MODE == 1) {
#pragma unroll
        for (int i = 0; i < 4; ++i)
            Ssum[(size_t)(b0 + lg * 4 + i) * 128 + c] = ssum[i];
    }
}

// ---------------------------------------------------------------------------
// BS branch + final head.  256 blocks x 512 thr; 16 rows/block; wave w owns
// cols [16w,16w+16) in every phase.  LDS handoffs; h0=0 => gh == bhh.
__global__ __launch_bounds__(512, 1) void k_bs_final(
    const float* __restrict__ s, const float* __restrict__ a,
    const u16* __restrict__ W1T, const float* __restrict__ b1,
    const u16* __restrict__ W2T, const float* __restrict__ b2,
    const u16* __restrict__ WIH0, const float* __restrict__ bih0,
    const float* __restrict__ bhh0,
    const u16* __restrict__ WIH1, const float* __restrict__ bih1,
    const float* __restrict__ bhh1,
    const float* __restrict__ Ssum,
    const u16* __restrict__ GATWT, const u16* __restrict__ EV1T,
    const float* __restrict__ ev1b, const float* __restrict__ ev2w,
    const float* __restrict__ ev2b, float* __restrict__ out)
{
    __shared__ __align__(16) u16 HBl[16][136];
    __shared__ __align__(16) u16 X2b[16][136];
    __shared__ __align__(16) u16 H0b[16][136];
    __shared__ __align__(16) float HLf[16][132];
    __shared__ __align__(16) u16 HBe[16][136];
    __shared__ __align__(16) float XBf[16][132];

    const int w = threadIdx.x >> 6, lane = threadIdx.x & 63;
    const int lm = lane & 15, lg = lane >> 4;
    const int r0 = blockIdx.x * 16;
    const int c = w * 16 + lm;                    // this wave's output column

    // ---- phase 1a: l1 (K=320) ----
    {
        const float* srow = s + (size_t)(r0 + lm) * 4352 + 4096 + lg * 8;
        const float* arow = a + (size_t)(r0 + lm) * 1088 + 1024 + lg * 8;
        bf16x8 af[10];
#pragma unroll
        for (int ks = 0; ks < 8; ++ks) af[ks] = ldfrag_f32(srow + ks * 32);
        af[8] = ldfrag_f32(arow);
        af[9] = ldfrag_f32(arow + 32);

        bf16x8 bw[10];
#pragma unroll
        for (int ks = 0; ks < 10; ++ks)
            bw[ks] = ldfrag(W1T + c * 320 + ks * 32 + lg * 8);
        floatx4 acc = {0.f, 0.f, 0.f, 0.f};
#pragma unroll
        for (int ks = 0; ks < 10; ++ks) acc = MFMA(af[ks], bw[ks], acc);
        const float bias = b1[c];
#pragma unroll
        for (int i = 0; i < 4; ++i) {
            float x = acc[i] + bias;
            HBl[lg * 4 + i][c] = f2b(x > 0.f ? x : 0.f);
        }
    }
    __syncthreads();

    // ---- phase 1b: l2 ----
    {
        bf16x8 af[4], bw[4];
#pragma unroll
        for (int ks = 0; ks < 4; ++ks) {
            af[ks] = ldfrag(&HBl[lm][ks * 32 + lg * 8]);
            bw[ks] = ldfrag(W2T + c * 128 + ks * 32 + lg * 8);
        }
        floatx4 acc = {0.f, 0.f, 0.f, 0.f};
#pragma unroll
        for (int ks = 0; ks < 4; ++ks) acc = MFMA(af[ks], bw[ks], acc);
        const float bias = b2[c];
#pragma unroll
        for (int i = 0; i < 4; ++i)
            X2b[lg * 4 + i][c] = f2b(sigm(acc[i] + bias));
    }
    __syncthreads();

    // ---- phase 2: gru0 (h0=0) ----
    {
        bf16x8 af[4], bw[3][4];
#pragma unroll
        for (int ks = 0; ks < 4; ++ks) {
            af[ks] = ldfrag(&X2b[lm][ks * 32 + lg * 8]);
#pragma unroll
            for (int g = 0; g < 3; ++g)
                bw[g][ks] = ldfrag(WIH0 + (g * 128 + c) * 128 + ks * 32 + lg * 8);
        }
        floatx4 aR{0,0,0,0}, aZ{0,0,0,0}, aN{0,0,0,0};
#pragma unroll
        for (int ks = 0; ks < 4; ++ks) {
            aR = MFMA(af[ks], bw[0][ks], aR);
            aZ = MFMA(af[ks], bw[1][ks], aZ);
            aN = MFMA(af[ks], bw[2][ks], aN);
        }
        const float brr = bih0[c] + bhh0[c];
        const float bzz = bih0[128 + c] + bhh0[128 + c];
        const float bni = bih0[256 + c], bnh = bhh0[256 + c];
#pragma unroll
        for (int i = 0; i < 4; ++i) {
            const float rr = sigm(aR[i] + brr);
            const float zz = sigm(aZ[i] + bzz);
            const float nn = tanh_(aN[i] + bni + rr * bnh);
            H0b[lg * 4 + i][c] = f2b((1.f - zz) * nn);
        }
    }
    __syncthreads();

    // ---- phase 3: gru1 (h0=0) -> HLf f32; also issue Ssum loads early ----
    float4 ssA[4], ssB[4];
    {
        const float* p1 = Ssum + (size_t)(r0 + lm) * 128 + lg * 8;
#pragma unroll
        for (int ks = 0; ks < 4; ++ks) {
            ssA[ks] = *reinterpret_cast<const float4*>(p1 + ks * 32);
            ssB[ks] = *reinterpret_cast<const float4*>(p1 + ks * 32 + 4);
        }
        bf16x8 af[4], bw[3][4];
#pragma unroll
        for (int ks = 0; ks < 4; ++ks) {
            af[ks] = ldfrag(&H0b[lm][ks * 32 + lg * 8]);
#pragma unroll
            for (int g = 0; g < 3; ++g)
                bw[g][ks] = ldfrag(WIH1 + (g * 128 + c) * 128 + ks * 32 + lg * 8);
        }
        floatx4 aR{0,0,0,0}, aZ{0,0,0,0}, aN{0,0,0,0};
#pragma unroll
        for (int ks = 0; ks < 4; ++ks) {
            aR = MFMA(af[ks], bw[0][ks], aR);
            aZ = MFMA(af[ks], bw[1][ks], aZ);
            aN = MFMA(af[ks], bw[2][ks], aN);
        }
        const float brr = bih1[c] + bhh1[c];
        const float bzz = bih1[128 + c] + bhh1[128 + c];
        const float bni = bih1[256 + c], bnh = bhh1[256 + c];
#pragma unroll
        for (int i = 0; i < 4; ++i) {
            const float rr = sigm(aR[i] + brr);
            const float zz = sigm(aZ[i] + bzz);
            const float nn = tanh_(aN[i] + bni + rr * bnh);
            HLf[lg * 4 + i][c] = (1.f - zz) * nn;
        }
    }
    __syncthreads();

    // ---- phase 4a: S = Ssum + HLf; elu(S @ gat_w) -> HBe ----
    {
        bf16x8 af[4], bw[4];
#pragma unroll
        for (int ks = 0; ks < 4; ++ks) {
            const float* hl = &HLf[lm][ks * 32 + lg * 8];
            float4 v  = *reinterpret_cast<const float4*>(hl);
            float4 v2 = *reinterpret_cast<const float4*>(hl + 4);
            short8 pk;
            pk[0] = (short)f2b(ssA[ks].x + v.x);  pk[1] = (short)f2b(ssA[ks].y + v.y);
            pk[2] = (short)f2b(ssA[ks].z + v.z);  pk[3] = (short)f2b(ssA[ks].w + v.w);
            pk[4] = (short)f2b(ssB[ks].x + v2.x); pk[5] = (short)f2b(ssB[ks].y + v2.y);
            pk[6] = (short)f2b(ssB[ks].z + v2.z); pk[7] = (short)f2b(ssB[ks].w + v2.w);
            af[ks] = __builtin_bit_cast(bf16x8, pk);
            bw[ks] = ldfrag(GATWT + c * 128 + ks * 32 + lg * 8);
        }
        floatx4 acc = {0.f, 0.f, 0.f, 0.f};
#pragma unroll
        for (int ks = 0; ks < 4; ++ks) acc = MFMA(af[ks], bw[ks], acc);
#pragma unroll
        for (int i = 0; i < 4; ++i) {
            float x = acc[i];
            x = x > 0.f ? x : (__expf(x) - 1.f);            // elu
            HBe[lg * 4 + i][c] = f2b(x);
        }
    }
    __syncthreads();

    // ---- phase 4b: relu(. @ ev1 + b1) -> XBf ----
    {
        bf16x8 af[4], bw[4];
#pragma unroll
        for (int ks = 0; ks < 4; ++ks) {
            af[ks] = ldfrag(&HBe[lm][ks * 32 + lg * 8]);
            bw[ks] = ldfrag(EV1T + c * 128 + ks * 32 + lg * 8);
        }
        floatx4 acc = {0.f, 0.f, 0.f, 0.f};
#pragma unroll
        for (int ks = 0; ks < 4; ++ks) acc = MFMA(af[ks], bw[ks], acc);
        const float bias = ev1b[c];
#pragma unroll
        for (int i = 0; i < 4; ++i) {
            float v = acc[i] + bias;
            XBf[lg * 4 + i][c] = v > 0.f ? v : 0.f;         // relu
        }
    }
    __syncthreads();

    // ---- phase 4c: out = XBf @ ev2 + b2 ----
    {
        const int row = threadIdx.x >> 5, l5 = threadIdx.x & 31;
        float sacc = 0.f;
#pragma unroll
        for (int j = 0; j < 4; ++j) {
            const int cc = l5 * 4 + j;
            sacc += XBf[row][cc] * ev2w[cc];
        }
#pragma unroll
        for (int d = 1; d < 32; d <<= 1) sacc += __shfl_xor(sacc, d, 64);
        if (l5 == 0) out[r0 + row] = sacc + ev2b[0];
    }
}

// ---------------------------------------------------------------------------
extern "C" void kernel_launch(void* const* d_in, const int* in_sizes, int n_in,
                              void* d_out, int out_size, void* d_ws, size_t ws_size,
                              hipStream_t stream)
{
    (void)in_sizes; (void)n_in; (void)out_size; (void)ws_size;
    const float* s       = (const float*)d_in[0];
    const float* a       = (const float*)d_in[1];
    const float* ue_l1_w = (const float*)d_in[2];
    const float* ue_l1_b = (const float*)d_in[3];
    const float* ue_l2_w = (const float*)d_in[4];
    const float* ue_l2_b = (const float*)d_in[5];
    const float* ue_wih0 = (const float*)d_in[6];
    const float* ue_whh0 = (const float*)d_in[7];
    const float* ue_bih0 = (const float*)d_in[8];
    const float* ue_bhh0 = (const float*)d_in[9];
    const float* ue_wih1 = (const float*)d_in[10];
    const float* ue_whh1 = (const float*)d_in[11];
    const float* ue_bih1 = (const float*)d_in[12];
    const float* ue_bhh1 = (const float*)d_in[13];
    const float* bs_l1_w = (const float*)d_in[14];
    const float* bs_l1_b = (const float*)d_in[15];
    const float* bs_l2_w = (const float*)d_in[16];
    const float* bs_l2_b = (const float*)d_in[17];
    const float* bs_wih0 = (const float*)d_in[18];
    const float* bs_bih0 = (const float*)d_in[20];
    const float* bs_bhh0 = (const float*)d_in[21];
    const float* bs_wih1 = (const float*)d_in[22];
    const float* bs_bih1 = (const float*)d_in[24];
    const float* bs_bhh1 = (const float*)d_in[25];
    const float* gat_w   = (const float*)d_in[26];
    const float* ev1_w   = (const float*)d_in[29];
    const float* ev1_b   = (const float*)d_in[30];
    const float* ev2_w   = (const float*)d_in[31];
    const float* ev2_b   = (const float*)d_in[32];

    char* ws = (char*)d_ws;
    u16*   wb   = (u16*)ws;
    u16*   X2   = (u16*)(ws + WB_X2);
    u16*   Y0   = (u16*)(ws + WB_Y0);
    float* SSUM = (float*)(ws + WB_SSUM);

    k_prep<<<256, 256, 0, stream>>>(ue_l1_w, ue_l2_w, ue_wih0, ue_whh0,
                                    ue_wih1, ue_whh1, bs_l1_w, bs_l2_w,
                                    bs_wih0, bs_wih1, gat_w, ev1_w, wb);
    k_ue_l1l2<<<1024, 512, 0, stream>>>(s, a, wb + O_UE_W1T, ue_l1_b,
                                        wb + O_UE_W2T, ue_l2_b, X2);
    k_scan<0><<<256, 512, 0, stream>>>(X2, wb + O_UE_WIH0, wb + O_UE_WHH0,
                                       ue_bih0, ue_bhh0, Y0, nullptr);
    k_scan<1><<<256, 512, 0, stream>>>(Y0, wb + O_UE_WIH1, wb + O_UE_WHH1,
                                       ue_bih1, ue_bhh1, nullptr, SSUM);
    k_bs_final<<<256, 512, 0, stream>>>(s, a, wb + O_BS_W1T, bs_l1_b,
                                        wb + O_BS_W2T, bs_l2_b,
                                        wb + O_BS_WIH0, bs_bih0, bs_bhh0,
                                        wb + O_BS_WIH1, bs_bih1, bs_bhh1,
                                        SSUM, wb + O_GATWT, wb + O_EV1T,
                                        ev1_b, ev2_w, ev2_b, (float*)d_out);
}